// Round 1
// baseline (773.262 us; speedup 1.0000x reference)
//
#include <hip/hip_runtime.h>

#define B_ 512
#define S_ 512
#define W_ 3
#define E_ 128
#define H_ 100
#define T_ 64
#define BS_ (B_*S_)

// ---------------------------------------------------------------------------
// Kernel A: fused embedding gather + MLP(tanh) + projection.
// One thread per (b,s) row. W1 staged in LDS (51.2 KB, broadcast reads);
// W2/b1/b2 read via uniform global loads (L1/scalar-cached).
// Writes em[b][s][t] (B,S,T) fp32 into workspace (64 MiB).
// ---------------------------------------------------------------------------
__global__ __launch_bounds__(256, 2) void mlp_kernel(
    const int* __restrict__ inputs, const float* __restrict__ tbl,
    const float* __restrict__ W1, const float* __restrict__ b1,
    const float* __restrict__ W2, const float* __restrict__ b2,
    float* __restrict__ em)
{
    __shared__ float sW1[E_*H_];   // 51200 B < 64 KB static limit
    {
        const float4* w4 = (const float4*)W1;
        float4* s4 = (float4*)sW1;
        for (int i = threadIdx.x; i < (E_*H_)/4; i += 256) s4[i] = w4[i];
    }
    __syncthreads();

    const int r = blockIdx.x * 256 + threadIdx.x;       // row id, exact grid
    const int i0 = inputs[r*3+0], i1 = inputs[r*3+1], i2 = inputs[r*3+2];

    const float4* r0 = (const float4*)tbl + (size_t)i0*(E_/4);
    const float4* r1 = (const float4*)tbl + (size_t)i1*(E_/4);
    const float4* r2 = (const float4*)tbl + (size_t)i2*(E_/4);

    float e[E_];
    #pragma unroll
    for (int q = 0; q < E_/4; ++q) {
        float4 a = r0[q], b = r1[q], c = r2[q];
        e[4*q+0] = a.x+b.x+c.x;
        e[4*q+1] = a.y+b.y+c.y;
        e[4*q+2] = a.z+b.z+c.z;
        e[4*q+3] = a.w+b.w+c.w;
    }

    float acc[T_];
    #pragma unroll
    for (int t = 0; t < T_; ++t) acc[t] = 0.f;

    // 25 iterations: compute 4 hidden units, immediately fold into em acc.
    for (int j0 = 0; j0 < H_; j0 += 4) {
        float4 bv = *(const float4*)(b1 + j0);
        float h0 = bv.x, h1 = bv.y, h2 = bv.z, h3 = bv.w;
        #pragma unroll
        for (int k = 0; k < E_; ++k) {
            const float4 w = *(const float4*)(&sW1[k*H_ + j0]);  // LDS broadcast
            float ev = e[k];
            h0 += ev*w.x; h1 += ev*w.y; h2 += ev*w.z; h3 += ev*w.w;
        }
        // tanh(x) = 1 - 2/(exp(2x)+1)  (stable at both extremes)
        h0 = 1.f - 2.f/(__expf(2.f*h0)+1.f);
        h1 = 1.f - 2.f/(__expf(2.f*h1)+1.f);
        h2 = 1.f - 2.f/(__expf(2.f*h2)+1.f);
        h3 = 1.f - 2.f/(__expf(2.f*h3)+1.f);

        const float4* w2r0 = (const float4*)(W2 + (size_t)(j0+0)*T_);
        const float4* w2r1 = (const float4*)(W2 + (size_t)(j0+1)*T_);
        const float4* w2r2 = (const float4*)(W2 + (size_t)(j0+2)*T_);
        const float4* w2r3 = (const float4*)(W2 + (size_t)(j0+3)*T_);
        #pragma unroll
        for (int q = 0; q < T_/4; ++q) {
            float4 w0 = w2r0[q], w1 = w2r1[q], w2v = w2r2[q], w3 = w2r3[q];
            acc[4*q+0] += h0*w0.x + h1*w1.x + h2*w2v.x + h3*w3.x;
            acc[4*q+1] += h0*w0.y + h1*w1.y + h2*w2v.y + h3*w3.y;
            acc[4*q+2] += h0*w0.z + h1*w1.z + h2*w2v.z + h3*w3.z;
            acc[4*q+3] += h0*w0.w + h1*w1.w + h2*w2v.w + h3*w3.w;
        }
    }

    float4* o4 = (float4*)(em + (size_t)r*T_);
    const float4* b24 = (const float4*)b2;
    #pragma unroll
    for (int q = 0; q < T_/4; ++q) {
        float4 bb = b24[q];
        o4[q] = make_float4(acc[4*q+0]+bb.x, acc[4*q+1]+bb.y,
                            acc[4*q+2]+bb.z, acc[4*q+3]+bb.w);
    }
}

// ---------------------------------------------------------------------------
// Kernel B: one wave per batch. Fused numerator + CRF forward scan.
// Rewrite: lse_i(a_i + trans_ij) = m + log(sum_i exp(a_i-m) * E_ij),
// E = exp(trans) constant -> per step: 1 exp/lane + 64-FMA matvec.
// Lane j owns alpha_j and E column j in 64 VGPRs; p broadcast via LDS.
// em reads software-pipelined 4 steps ahead (only 2 waves/CU -> no TLP).
// ---------------------------------------------------------------------------
__global__ __launch_bounds__(64) void crf_kernel(
    const int* __restrict__ inputs, const int* __restrict__ tags,
    const float* __restrict__ em, const float* __restrict__ start_trans,
    const float* __restrict__ end_trans, const float* __restrict__ trans,
    float* __restrict__ out)
{
    __shared__ float4 pbuf4[T_/4];
    __shared__ float maskArr[S_];

    const int b = blockIdx.x;
    const int j = threadIdx.x;
    const float* emb_b = em + (size_t)b*S_*T_;
    const int* tags_b = tags + b*S_;
    const int* in_b = inputs + (size_t)b*S_*3;

    // ---- numerator + mask precompute (lane-parallel over t) ----
    float partial = 0.f;
    int mcount = 0;
    for (int t = j; t < S_; t += 64) {
        int a0 = in_b[t*3+0], a1 = in_b[t*3+1], a2 = in_b[t*3+2];
        int any = (a0 | a1 | a2);          // values >= 0; nonzero iff any != PAD(0)
        float mk = (any != 0) ? 1.f : 0.f;
        maskArr[t] = mk;
        mcount += (any != 0) ? 1 : 0;
        if (t >= 1) {
            int tp = tags_b[t-1], tc = tags_b[t];
            partial += mk * (trans[tp*T_ + tc] + emb_b[(size_t)t*T_ + tc]);
        }
    }
    #pragma unroll
    for (int off = 32; off >= 1; off >>= 1) {
        partial += __shfl_xor(partial, off, 64);
        mcount  += __shfl_xor(mcount, off, 64);
    }
    const int tag0 = tags_b[0];
    int seq_end = mcount - 1; if (seq_end < 0) seq_end = 0;
    const int last_tag = tags_b[seq_end];
    const float numer = partial + start_trans[tag0] + emb_b[tag0] + end_trans[last_tag];

    __syncthreads();   // maskArr visible (single wave, but cheap & safe)

    // E column j in registers (constant across the scan)
    float Ecol[T_];
    #pragma unroll
    for (int i = 0; i < T_; ++i) Ecol[i] = __expf(trans[i*T_ + j]);

    float alpha = start_trans[j] + emb_b[j];   // t = 0, unconditional

    // 4-deep em prefetch pipeline
    float em_pipe[4];
    #pragma unroll
    for (int c = 0; c < 4; ++c) em_pipe[c] = emb_b[(size_t)(1+c)*T_ + j];

    auto step = [&](float em_t, int t) {
        float m = alpha;
        #pragma unroll
        for (int off = 32; off >= 1; off >>= 1) m = fmaxf(m, __shfl_xor(m, off, 64));
        float p = __expf(alpha - m);
        ((float*)pbuf4)[j] = p;
        __builtin_amdgcn_wave_barrier();   // keep write before reads (wave-lockstep, DS in-order)
        float d0 = 0.f, d1 = 0.f, d2 = 0.f, d3 = 0.f;
        #pragma unroll
        for (int q = 0; q < 4; ++q) {
            float4 A = pbuf4[4*q+0], Bv = pbuf4[4*q+1], C = pbuf4[4*q+2], D = pbuf4[4*q+3];
            d0 += A.x *Ecol[16*q+ 0] + A.y *Ecol[16*q+ 1] + A.z *Ecol[16*q+ 2] + A.w *Ecol[16*q+ 3];
            d1 += Bv.x*Ecol[16*q+ 4] + Bv.y*Ecol[16*q+ 5] + Bv.z*Ecol[16*q+ 6] + Bv.w*Ecol[16*q+ 7];
            d2 += C.x *Ecol[16*q+ 8] + C.y *Ecol[16*q+ 9] + C.z *Ecol[16*q+10] + C.w *Ecol[16*q+11];
            d3 += D.x *Ecol[16*q+12] + D.y *Ecol[16*q+13] + D.z *Ecol[16*q+14] + D.w *Ecol[16*q+15];
        }
        float dot = (d0+d1)+(d2+d3);
        float nxt = em_t + m + __logf(dot);
        float mk = maskArr[t];
        alpha = (mk != 0.f) ? nxt : alpha;
        __builtin_amdgcn_wave_barrier();
    };

    int t = 1;
    for (int g = 0; g < 127; ++g) {          // t = 1 .. 508
        #pragma unroll
        for (int c = 0; c < 4; ++c) {
            float em_t = em_pipe[c];
            int tf = t + 4;
            em_pipe[c] = (tf < S_) ? emb_b[(size_t)tf*T_ + j] : 0.f;
            step(em_t, t);
            ++t;
        }
    }
    step(em_pipe[0], 509);
    step(em_pipe[1], 510);
    step(em_pipe[2], 511);

    // denominator = lse_j(alpha_j + end_trans_j)
    float x = alpha + end_trans[j];
    float m2 = x;
    #pragma unroll
    for (int off = 32; off >= 1; off >>= 1) m2 = fmaxf(m2, __shfl_xor(m2, off, 64));
    float s = __expf(x - m2);
    #pragma unroll
    for (int off = 32; off >= 1; off >>= 1) s += __shfl_xor(s, off, 64);
    float denom = m2 + __logf(s);

    if (j == 0) out[b] = denom - numer;
}

// ---------------------------------------------------------------------------
extern "C" void kernel_launch(void* const* d_in, const int* in_sizes, int n_in,
                              void* d_out, int out_size, void* d_ws, size_t ws_size,
                              hipStream_t stream) {
    const int*   inputs      = (const int*)  d_in[0];
    const int*   tags        = (const int*)  d_in[1];
    const float* emb_table   = (const float*)d_in[2];
    const float* W1          = (const float*)d_in[3];
    const float* b1          = (const float*)d_in[4];
    const float* W2          = (const float*)d_in[5];
    const float* b2          = (const float*)d_in[6];
    const float* start_trans = (const float*)d_in[7];
    const float* end_trans   = (const float*)d_in[8];
    const float* transitions = (const float*)d_in[9];
    float* out = (float*)d_out;

    float* em = (float*)d_ws;   // B*S*T fp32 = 64 MiB workspace

    mlp_kernel<<<dim3(BS_/256), dim3(256), 0, stream>>>(
        inputs, emb_table, W1, b1, W2, b2, em);
    crf_kernel<<<dim3(B_), dim3(64), 0, stream>>>(
        inputs, tags, em, start_trans, end_trans, transitions, out);
}

// Round 2
// 508.401 us; speedup vs baseline: 1.5210x; 1.5210x over previous
//
#include <hip/hip_runtime.h>

#define B_ 512
#define S_ 512
#define E_ 128
#define H_ 100
#define T_ 64
#define BS_ (B_*S_)

typedef __attribute__((ext_vector_type(8))) short bf16x8;
typedef __attribute__((ext_vector_type(4))) float f32x4;
union U16x4 { uint4 u; bf16x8 s; };

__device__ __forceinline__ unsigned f2bf1(float x){
    unsigned u = __float_as_uint(x);
    return (u + 0x7FFFu + ((u>>16)&1u)) >> 16;
}
__device__ __forceinline__ float bf2f(unsigned short h){
    return __uint_as_float(((unsigned)h)<<16);
}

// ---------------------------------------------------------------------------
// Prep: build W1/W2 bf16 MFMA B-fragment images in ws (one tiny block).
// Frag k-map (BOTH operands, consistency is what matters): k=(lane>>4)*8+i.
// W1f[(nt*4+kt)*64+lane], nt<7 (N=112 pad), kt<4 (K=128).
// W2f[(nt*4+kt)*64+lane], nt<4 (N=64),      kt<4 (K=128 pad, rows>=100 zero).
// ---------------------------------------------------------------------------
__global__ void prep_kernel(const float* __restrict__ W1, const float* __restrict__ W2,
                            uint4* __restrict__ W1f, uint4* __restrict__ W2f)
{
    const int tid = threadIdx.x;
    for (int idx = tid; idx < 7*4*64; idx += 256) {
        int lane = idx & 63, kt = (idx>>6)&3, nt = idx>>8;
        int n = nt*16 + (lane&15);
        int kb = kt*32 + (lane>>4)*8;
        unsigned wv[4];
        #pragma unroll
        for (int p = 0; p < 4; ++p) {
            float v0 = (n < H_) ? W1[(kb+2*p  )*H_ + n] : 0.f;
            float v1 = (n < H_) ? W1[(kb+2*p+1)*H_ + n] : 0.f;
            wv[p] = f2bf1(v0) | (f2bf1(v1) << 16);
        }
        W1f[idx] = make_uint4(wv[0],wv[1],wv[2],wv[3]);
    }
    for (int idx = tid; idx < 4*4*64; idx += 256) {
        int lane = idx & 63, kt = (idx>>6)&3, nt = idx>>8;
        int n = nt*16 + (lane&15);
        int kb = kt*32 + (lane>>4)*8;
        unsigned wv[4];
        #pragma unroll
        for (int p = 0; p < 4; ++p) {
            int k0 = kb+2*p, k1 = kb+2*p+1;
            float v0 = (k0 < H_) ? W2[k0*T_ + n] : 0.f;
            float v1 = (k1 < H_) ? W2[k1*T_ + n] : 0.f;
            wv[p] = f2bf1(v0) | (f2bf1(v1) << 16);
        }
        W2f[idx] = make_uint4(wv[0],wv[1],wv[2],wv[3]);
    }
}

// ---------------------------------------------------------------------------
// MLP: 64 rows/block, 4 waves (1 m-tile each). gather-sum -> bf16 A frags in
// LDS -> GEMM1 (K=128) -> tanh -> A2 frags (alias sXf, wave-local) -> GEMM2
// (K=128 pad) -> em bf16 (B,S,T). LDS 60KB -> 2 blocks/CU.
// ---------------------------------------------------------------------------
__global__ __launch_bounds__(256, 2) void mlp_kernel(
    const int* __restrict__ inputs, const float* __restrict__ tbl,
    const float* __restrict__ b1, const float* __restrict__ b2,
    const uint4* __restrict__ W1f, const uint4* __restrict__ W2f,
    unsigned short* __restrict__ em)
{
    __shared__ uint4 sW1f[1792];   // 28 KB
    __shared__ uint4 sW2f[1024];   // 16 KB
    __shared__ uint4 sXf[1024];    // 16 KB; reused as A2 after GEMM1

    const int tid = threadIdx.x;
    for (int i = tid; i < 1792; i += 256) sW1f[i] = W1f[i];
    for (int i = tid; i < 1024; i += 256) sW2f[i] = W2f[i];

    // gather-sum + stage X fragments: thread = (row r = tid>>2, k-tile = tid&3)
    {
        const int r  = tid >> 2;
        const int kt = tid & 3;
        const int rg = blockIdx.x*64 + r;
        const int i0 = inputs[rg*3+0], i1 = inputs[rg*3+1], i2 = inputs[rg*3+2];
        const float4* q0 = (const float4*)tbl + (size_t)i0*(E_/4) + kt*8;
        const float4* q1 = (const float4*)tbl + (size_t)i1*(E_/4) + kt*8;
        const float4* q2 = (const float4*)tbl + (size_t)i2*(E_/4) + kt*8;
        float v[32];
        #pragma unroll
        for (int q = 0; q < 8; ++q) {
            float4 x0 = q0[q], x1 = q1[q], x2 = q2[q];
            v[4*q+0] = x0.x+x1.x+x2.x;
            v[4*q+1] = x0.y+x1.y+x2.y;
            v[4*q+2] = x0.z+x1.z+x2.z;
            v[4*q+3] = x0.w+x1.w+x2.w;
        }
        const int mt = r >> 4;
        #pragma unroll
        for (int g = 0; g < 4; ++g) {
            uint4 wv;
            wv.x = f2bf1(v[g*8+0]) | (f2bf1(v[g*8+1])<<16);
            wv.y = f2bf1(v[g*8+2]) | (f2bf1(v[g*8+3])<<16);
            wv.z = f2bf1(v[g*8+4]) | (f2bf1(v[g*8+5])<<16);
            wv.w = f2bf1(v[g*8+6]) | (f2bf1(v[g*8+7])<<16);
            sXf[(mt*4+kt)*64 + g*16 + (r&15)] = wv;
        }
    }
    __syncthreads();

    const int lane  = tid & 63;
    const int w     = tid >> 6;          // m-tile of this wave
    const int col   = lane & 15;
    const int rowin = (lane >> 4) * 4;   // + reg  (m89-verified C/D layout)

    // GEMM1: h(16x112) = X(16x128) @ W1(128x112), bias in acc init
    U16x4 a[4];
    #pragma unroll
    for (int k = 0; k < 4; ++k) a[k].u = sXf[(w*4+k)*64 + lane];
    f32x4 acc1[7];
    #pragma unroll
    for (int nt = 0; nt < 7; ++nt) {
        int n = nt*16 + col;
        float bv = (n < H_) ? b1[n] : 0.f;
        f32x4 c; c[0]=bv; c[1]=bv; c[2]=bv; c[3]=bv;
        #pragma unroll
        for (int k = 0; k < 4; ++k) {
            U16x4 bfr; bfr.u = sW1f[(nt*4+k)*64 + lane];
            c = __builtin_amdgcn_mfma_f32_16x16x32_bf16(a[k].s, bfr.s, c, 0,0,0);
        }
        acc1[nt] = c;
    }
    // tanh (stable both tails)
    #pragma unroll
    for (int nt = 0; nt < 7; ++nt)
        #pragma unroll
        for (int rr = 0; rr < 4; ++rr) {
            float x = acc1[nt][rr];
            acc1[nt][rr] = 1.f - 2.f/(__expf(2.f*x)+1.f);
        }

    // A2 fragment staging into sXf (wave-local region; done reading Xf).
    // k2 = h-column; pad k2=112..127 with zeros (frag lanes 32..63 of kt2=3).
    if (lane >= 32) sXf[(w*4+3)*64 + lane] = make_uint4(0,0,0,0);
    unsigned short* A2h = (unsigned short*)sXf;
    #pragma unroll
    for (int nt = 0; nt < 7; ++nt)
        #pragma unroll
        for (int rr = 0; rr < 4; ++rr) {
            int k2 = nt*16 + col;
            int kt2 = k2 >> 5, g2 = (k2>>3)&3, i2 = k2&7;
            int u4idx = (w*4 + kt2)*64 + g2*16 + (rowin + rr);
            A2h[u4idx*8 + i2] = (unsigned short)f2bf1(acc1[nt][rr]);
        }

    // GEMM2: em(16x64) = h(16x128pad) @ W2(128pad x 64), bias b2 in acc init
    U16x4 a2[4];
    #pragma unroll
    for (int k = 0; k < 4; ++k) a2[k].u = sXf[(w*4+k)*64 + lane];
    #pragma unroll
    for (int nt2 = 0; nt2 < 4; ++nt2) {
        float bv = b2[nt2*16 + col];
        f32x4 c; c[0]=bv; c[1]=bv; c[2]=bv; c[3]=bv;
        #pragma unroll
        for (int k = 0; k < 4; ++k) {
            U16x4 bfr; bfr.u = sW2f[(nt2*4+k)*64 + lane];
            c = __builtin_amdgcn_mfma_f32_16x16x32_bf16(a2[k].s, bfr.s, c, 0,0,0);
        }
        #pragma unroll
        for (int rr = 0; rr < 4; ++rr) {
            size_t row = (size_t)(blockIdx.x*64 + w*16 + rowin + rr);
            em[row*T_ + nt2*16 + col] = (unsigned short)f2bf1(c[rr]);
        }
    }
}

// ---------------------------------------------------------------------------
// CRF scan: one wave per batch. lse_i(a_i+trans_ij) = m + log(sum p_i E_ij).
// Per-step chain trimmed: readfirstlane offset (no shfl max-reduce), mask in
// SGPR ballots (no per-step LDS read), t=0 folded in with cleared mask bit.
// ---------------------------------------------------------------------------
__global__ __launch_bounds__(64) void crf_kernel(
    const int* __restrict__ inputs, const int* __restrict__ tags,
    const unsigned short* __restrict__ em, const float* __restrict__ start_trans,
    const float* __restrict__ end_trans, const float* __restrict__ trans,
    float* __restrict__ out)
{
    __shared__ float pbuf[T_];
    const int b = blockIdx.x;
    const int j = threadIdx.x;
    const unsigned short* em_b = em + (size_t)b*S_*T_;
    const int* tags_b = tags + b*S_;
    const int* in_b = inputs + (size_t)b*S_*3;

    // mask ballots + numerator partial
    unsigned long long mball[8];
    float partial = 0.f;
    #pragma unroll
    for (int g = 0; g < 8; ++g) {
        int t = g*64 + j;
        int a0 = in_b[t*3+0], a1 = in_b[t*3+1], a2 = in_b[t*3+2];
        bool mk = ((a0 | a1 | a2) != 0);
        mball[g] = __ballot(mk);
        if (t >= 1 && mk) {
            int tp = tags_b[t-1], tc = tags_b[t];
            partial += trans[tp*T_ + tc] + bf2f(em_b[(size_t)t*T_ + tc]);
        }
    }
    int mcount = 0;
    #pragma unroll
    for (int g = 0; g < 8; ++g) mcount += __popcll(mball[g]);
    mball[0] &= ~1ull;                      // t=0 is not a scan step
    #pragma unroll
    for (int off = 32; off >= 1; off >>= 1) partial += __shfl_xor(partial, off, 64);
    const int tag0 = tags_b[0];
    int se = mcount - 1; if (se < 0) se = 0;
    const int last_tag = tags_b[se];
    const float numer = partial + start_trans[tag0] + bf2f(em_b[tag0]) + end_trans[last_tag];

    // E column j (constant over scan), coalesced loads
    float Ecol[T_];
    #pragma unroll
    for (int i = 0; i < T_; ++i) Ecol[i] = __expf(trans[i*T_ + j]);

    float alpha = start_trans[j] + bf2f(em_b[j]);

    float pipe[4];
    #pragma unroll
    for (int c = 0; c < 4; ++c) pipe[c] = bf2f(em_b[c*T_ + j]);

    int t = 0;
    #pragma unroll
    for (int blk = 0; blk < 8; ++blk) {
        const unsigned long long mg = mball[blk];
        for (int q = 0; q < 16; ++q) {
            #pragma unroll
            for (int c = 0; c < 4; ++c) {
                float em_t = pipe[c];
                int tf = t + 4;
                pipe[c] = (tf < S_) ? bf2f(em_b[(size_t)tf*T_ + j]) : 0.f;

                float m0 = __uint_as_float(__builtin_amdgcn_readfirstlane(__float_as_uint(alpha)));
                float p = __expf(alpha - m0);
                pbuf[j] = p;
                const float4* pb4 = (const float4*)pbuf;
                float d0=0.f, d1=0.f, d2=0.f, d3=0.f;
                #pragma unroll
                for (int qq = 0; qq < 4; ++qq) {
                    float4 A = pb4[4*qq+0], Bv = pb4[4*qq+1], C = pb4[4*qq+2], D = pb4[4*qq+3];
                    d0 += A.x *Ecol[16*qq+ 0] + A.y *Ecol[16*qq+ 1] + A.z *Ecol[16*qq+ 2] + A.w *Ecol[16*qq+ 3];
                    d1 += Bv.x*Ecol[16*qq+ 4] + Bv.y*Ecol[16*qq+ 5] + Bv.z*Ecol[16*qq+ 6] + Bv.w*Ecol[16*qq+ 7];
                    d2 += C.x *Ecol[16*qq+ 8] + C.y *Ecol[16*qq+ 9] + C.z *Ecol[16*qq+10] + C.w *Ecol[16*qq+11];
                    d3 += D.x *Ecol[16*qq+12] + D.y *Ecol[16*qq+13] + D.z *Ecol[16*qq+14] + D.w *Ecol[16*qq+15];
                }
                float dot = (d0+d1)+(d2+d3);
                float nxt = em_t + m0 + __logf(dot);
                bool bit = (mg >> (q*4 + c)) & 1ull;
                alpha = bit ? nxt : alpha;
                ++t;
            }
        }
    }

    // denominator = lse_j(alpha_j + end_trans_j)
    float x = alpha + end_trans[j];
    float m2 = x;
    #pragma unroll
    for (int off = 32; off >= 1; off >>= 1) m2 = fmaxf(m2, __shfl_xor(m2, off, 64));
    float s = __expf(x - m2);
    #pragma unroll
    for (int off = 32; off >= 1; off >>= 1) s += __shfl_xor(s, off, 64);
    if (j == 0) out[b] = m2 + __logf(s) - numer;
}

// ---------------------------------------------------------------------------
extern "C" void kernel_launch(void* const* d_in, const int* in_sizes, int n_in,
                              void* d_out, int out_size, void* d_ws, size_t ws_size,
                              hipStream_t stream) {
    const int*   inputs      = (const int*)  d_in[0];
    const int*   tags        = (const int*)  d_in[1];
    const float* emb_table   = (const float*)d_in[2];
    const float* W1          = (const float*)d_in[3];
    const float* b1          = (const float*)d_in[4];
    const float* W2          = (const float*)d_in[5];
    const float* b2          = (const float*)d_in[6];
    const float* start_trans = (const float*)d_in[7];
    const float* end_trans   = (const float*)d_in[8];
    const float* transitions = (const float*)d_in[9];
    float* out = (float*)d_out;

    // ws: em bf16 (32 MiB) | W1f frags (28 KB) | W2f frags (16 KB)
    unsigned short* em = (unsigned short*)d_ws;
    uint4* W1f = (uint4*)((char*)d_ws + (size_t)BS_*T_*2);
    uint4* W2f = W1f + 7*4*64;

    prep_kernel<<<dim3(1), dim3(256), 0, stream>>>(W1, W2, W1f, W2f);
    mlp_kernel<<<dim3(BS_/64), dim3(256), 0, stream>>>(
        inputs, emb_table, b1, b2, W1f, W2f, em);
    crf_kernel<<<dim3(B_), dim3(64), 0, stream>>>(
        inputs, tags, em, start_trans, end_trans, transitions, out);
}

// Round 3
// 371.042 us; speedup vs baseline: 2.0840x; 1.3702x over previous
//
#include <hip/hip_runtime.h>

#define B_ 512
#define S_ 512
#define E_ 128
#define H_ 100
#define T_ 64
#define BS_ (B_*S_)

typedef __attribute__((ext_vector_type(8))) short bf16x8;
typedef __attribute__((ext_vector_type(4))) float f32x4;
union U16x4 { uint4 u; bf16x8 s; };

__device__ __forceinline__ unsigned f2bf1(float x){
    unsigned u = __float_as_uint(x);
    return (u + 0x7FFFu + ((u>>16)&1u)) >> 16;
}
__device__ __forceinline__ float bf2f(unsigned short h){
    return __uint_as_float(((unsigned)h)<<16);
}

// ---------------------------------------------------------------------------
// Prep: build W1/W2 bf16 MFMA B-fragment images in ws (one tiny block).
// Frag k-map (BOTH operands, consistency is what matters): k=(lane>>4)*8+i.
// ---------------------------------------------------------------------------
__global__ void prep_kernel(const float* __restrict__ W1, const float* __restrict__ W2,
                            uint4* __restrict__ W1f, uint4* __restrict__ W2f)
{
    const int tid = threadIdx.x;
    for (int idx = tid; idx < 7*4*64; idx += 256) {
        int lane = idx & 63, kt = (idx>>6)&3, nt = idx>>8;
        int n = nt*16 + (lane&15);
        int kb = kt*32 + (lane>>4)*8;
        unsigned wv[4];
        #pragma unroll
        for (int p = 0; p < 4; ++p) {
            float v0 = (n < H_) ? W1[(kb+2*p  )*H_ + n] : 0.f;
            float v1 = (n < H_) ? W1[(kb+2*p+1)*H_ + n] : 0.f;
            wv[p] = f2bf1(v0) | (f2bf1(v1) << 16);
        }
        W1f[idx] = make_uint4(wv[0],wv[1],wv[2],wv[3]);
    }
    for (int idx = tid; idx < 4*4*64; idx += 256) {
        int lane = idx & 63, kt = (idx>>6)&3, nt = idx>>8;
        int n = nt*16 + (lane&15);
        int kb = kt*32 + (lane>>4)*8;
        unsigned wv[4];
        #pragma unroll
        for (int p = 0; p < 4; ++p) {
            int k0 = kb+2*p, k1 = kb+2*p+1;
            float v0 = (k0 < H_) ? W2[k0*T_ + n] : 0.f;
            float v1 = (k1 < H_) ? W2[k1*T_ + n] : 0.f;
            wv[p] = f2bf1(v0) | (f2bf1(v1) << 16);
        }
        W2f[idx] = make_uint4(wv[0],wv[1],wv[2],wv[3]);
    }
}

// ---------------------------------------------------------------------------
// MLP: 64 rows/block, 4 waves. W fragments read straight from global (L2-hot,
// block-invariant) -> LDS is just the 16 KB X/A2 buffer -> 4 blocks/CU.
// ---------------------------------------------------------------------------
__global__ __launch_bounds__(256, 4) void mlp_kernel(
    const int* __restrict__ inputs, const float* __restrict__ tbl,
    const float* __restrict__ b1, const float* __restrict__ b2,
    const uint4* __restrict__ W1f, const uint4* __restrict__ W2f,
    unsigned short* __restrict__ em)
{
    __shared__ uint4 sXf[1024];    // 16 KB; X frags, reused as A2 after GEMM1

    const int tid = threadIdx.x;

    // gather-sum + stage X fragments: thread = (row r = tid>>2, k-tile = tid&3)
    {
        const int r  = tid >> 2;
        const int kt = tid & 3;
        const int rg = blockIdx.x*64 + r;
        const int i0 = inputs[rg*3+0], i1 = inputs[rg*3+1], i2 = inputs[rg*3+2];
        const float4* q0 = (const float4*)tbl + (size_t)i0*(E_/4) + kt*8;
        const float4* q1 = (const float4*)tbl + (size_t)i1*(E_/4) + kt*8;
        const float4* q2 = (const float4*)tbl + (size_t)i2*(E_/4) + kt*8;
        float v[32];
        #pragma unroll
        for (int q = 0; q < 8; ++q) {
            float4 x0 = q0[q], x1 = q1[q], x2 = q2[q];
            v[4*q+0] = x0.x+x1.x+x2.x;
            v[4*q+1] = x0.y+x1.y+x2.y;
            v[4*q+2] = x0.z+x1.z+x2.z;
            v[4*q+3] = x0.w+x1.w+x2.w;
        }
        const int mt = r >> 4;
        #pragma unroll
        for (int g = 0; g < 4; ++g) {
            uint4 wv;
            wv.x = f2bf1(v[g*8+0]) | (f2bf1(v[g*8+1])<<16);
            wv.y = f2bf1(v[g*8+2]) | (f2bf1(v[g*8+3])<<16);
            wv.z = f2bf1(v[g*8+4]) | (f2bf1(v[g*8+5])<<16);
            wv.w = f2bf1(v[g*8+6]) | (f2bf1(v[g*8+7])<<16);
            sXf[(mt*4+kt)*64 + g*16 + (r&15)] = wv;
        }
    }
    __syncthreads();

    const int lane  = tid & 63;
    const int w     = tid >> 6;          // m-tile of this wave
    const int col   = lane & 15;
    const int rowin = (lane >> 4) * 4;   // + reg  (m89-verified C/D layout)

    // GEMM1: h(16x112) = X(16x128) @ W1(128x112); W1 frags from global (L2)
    U16x4 a[4];
    #pragma unroll
    for (int k = 0; k < 4; ++k) a[k].u = sXf[(w*4+k)*64 + lane];
    f32x4 acc1[7];
    #pragma unroll
    for (int nt = 0; nt < 7; ++nt) {
        int n = nt*16 + col;
        float bv = (n < H_) ? b1[n] : 0.f;
        f32x4 c; c[0]=bv; c[1]=bv; c[2]=bv; c[3]=bv;
        #pragma unroll
        for (int k = 0; k < 4; ++k) {
            U16x4 bfr; bfr.u = W1f[(nt*4+k)*64 + lane];
            c = __builtin_amdgcn_mfma_f32_16x16x32_bf16(a[k].s, bfr.s, c, 0,0,0);
        }
        acc1[nt] = c;
    }
    // tanh (stable both tails)
    #pragma unroll
    for (int nt = 0; nt < 7; ++nt)
        #pragma unroll
        for (int rr = 0; rr < 4; ++rr) {
            float x = acc1[nt][rr];
            acc1[nt][rr] = 1.f - 2.f/(__expf(2.f*x)+1.f);
        }

    // A2 fragment staging into sXf (wave-local region; done reading Xf).
    if (lane >= 32) sXf[(w*4+3)*64 + lane] = make_uint4(0,0,0,0);
    unsigned short* A2h = (unsigned short*)sXf;
    #pragma unroll
    for (int nt = 0; nt < 7; ++nt)
        #pragma unroll
        for (int rr = 0; rr < 4; ++rr) {
            int k2 = nt*16 + col;
            int kt2 = k2 >> 5, g2 = (k2>>3)&3, i2 = k2&7;
            int u4idx = (w*4 + kt2)*64 + g2*16 + (rowin + rr);
            A2h[u4idx*8 + i2] = (unsigned short)f2bf1(acc1[nt][rr]);
        }

    // GEMM2: em(16x64) = h(16x128pad) @ W2(128pad x 64); W2 frags from global
    U16x4 a2[4];
    #pragma unroll
    for (int k = 0; k < 4; ++k) a2[k].u = sXf[(w*4+k)*64 + lane];
    #pragma unroll
    for (int nt2 = 0; nt2 < 4; ++nt2) {
        float bv = b2[nt2*16 + col];
        f32x4 c; c[0]=bv; c[1]=bv; c[2]=bv; c[3]=bv;
        #pragma unroll
        for (int k = 0; k < 4; ++k) {
            U16x4 bfr; bfr.u = W2f[(nt2*4+k)*64 + lane];
            c = __builtin_amdgcn_mfma_f32_16x16x32_bf16(a2[k].s, bfr.s, c, 0,0,0);
        }
        #pragma unroll
        for (int rr = 0; rr < 4; ++rr) {
            size_t row = (size_t)(blockIdx.x*64 + w*16 + rowin + rr);
            em[row*T_ + nt2*16 + col] = (unsigned short)f2bf1(c[rr]);
        }
    }
}

// ---------------------------------------------------------------------------
// CRF scan: one wave per batch. Group-of-8 em staging: one coalesced uint4
// global load per lane per 8 steps (64 lanes x 16B = 8 rows), double-buffered
// through LDS; per-step em comes from ds_read_u16 (latency trivially hidden).
// No global loads on the step chain.
// ---------------------------------------------------------------------------
__global__ __launch_bounds__(64) void crf_kernel(
    const int* __restrict__ inputs, const int* __restrict__ tags,
    const unsigned short* __restrict__ em, const float* __restrict__ start_trans,
    const float* __restrict__ end_trans, const float* __restrict__ trans,
    float* __restrict__ out)
{
    __shared__ unsigned short sem[2][8*T_];   // 2 x 1 KB em staging
    __shared__ float pbuf[T_];

    const int b = blockIdx.x;
    const int j = threadIdx.x;
    const unsigned short* em_b = em + (size_t)b*S_*T_;
    const int* tags_b = tags + b*S_;
    const int* in_b = inputs + (size_t)b*S_*3;

    // mask ballots + numerator partial
    unsigned long long mball[8];
    float partial = 0.f;
    #pragma unroll
    for (int g = 0; g < 8; ++g) {
        int t = g*64 + j;
        int a0 = in_b[t*3+0], a1 = in_b[t*3+1], a2 = in_b[t*3+2];
        bool mk = ((a0 | a1 | a2) != 0);
        mball[g] = __ballot(mk);
        if (t >= 1 && mk) {
            int tp = tags_b[t-1], tc = tags_b[t];
            partial += trans[tp*T_ + tc] + bf2f(em_b[(size_t)t*T_ + tc]);
        }
    }
    int mcount = 0;
    #pragma unroll
    for (int g = 0; g < 8; ++g) mcount += __popcll(mball[g]);
    mball[0] &= ~1ull;                      // t=0 is not a scan step
    #pragma unroll
    for (int off = 32; off >= 1; off >>= 1) partial += __shfl_xor(partial, off, 64);
    const int tag0 = tags_b[0];
    int se = mcount - 1; if (se < 0) se = 0;
    const int last_tag = tags_b[se];
    const float numer = partial + start_trans[tag0] + bf2f(em_b[tag0]) + end_trans[last_tag];

    // E column j (constant over scan), coalesced loads
    float Ecol[T_];
    #pragma unroll
    for (int i = 0; i < T_; ++i) Ecol[i] = __expf(trans[i*T_ + j]);

    float alpha = start_trans[j] + bf2f(em_b[j]);

    const uint4* em4 = (const uint4*)em_b;    // 64 uint4 per 8-row group
    uint4 gbuf = em4[j];                      // group 0 (rows 0..7)

    for (int g = 0; g < 64; ++g) {
        ((uint4*)sem[g&1])[j] = gbuf;
        if (g < 63) gbuf = em4[(g+1)*64 + j];           // next group, off-chain
        __builtin_amdgcn_wave_barrier();
        // em values for this group's 8 steps (issued together; DS in-order)
        float emg[8];
        #pragma unroll
        for (int c = 0; c < 8; ++c) emg[c] = bf2f(sem[g&1][c*T_ + j]);
        const unsigned mg = (unsigned)((mball[g>>3] >> ((g&7)*8)) & 0xFFull);

        #pragma unroll
        for (int c = 0; c < 8; ++c) {
            float m0 = __uint_as_float(__builtin_amdgcn_readfirstlane(__float_as_uint(alpha)));
            float p = __expf(alpha - m0);
            pbuf[j] = p;
            __builtin_amdgcn_wave_barrier();
            const float4* pb4 = (const float4*)pbuf;
            float d[8];
            #pragma unroll
            for (int h = 0; h < 8; ++h) {
                float4 A = pb4[2*h], Bv = pb4[2*h+1];
                d[h] = A.x *Ecol[8*h+0] + A.y *Ecol[8*h+1] + A.z *Ecol[8*h+2] + A.w *Ecol[8*h+3]
                     + Bv.x*Ecol[8*h+4] + Bv.y*Ecol[8*h+5] + Bv.z*Ecol[8*h+6] + Bv.w*Ecol[8*h+7];
            }
            float dot = ((d[0]+d[1])+(d[2]+d[3])) + ((d[4]+d[5])+(d[6]+d[7]));
            float nxt = emg[c] + m0 + __logf(dot);
            alpha = ((mg >> c) & 1u) ? nxt : alpha;
            __builtin_amdgcn_wave_barrier();
        }
    }

    // denominator = lse_j(alpha_j + end_trans_j)
    float x = alpha + end_trans[j];
    float m2 = x;
    #pragma unroll
    for (int off = 32; off >= 1; off >>= 1) m2 = fmaxf(m2, __shfl_xor(m2, off, 64));
    float s = __expf(x - m2);
    #pragma unroll
    for (int off = 32; off >= 1; off >>= 1) s += __shfl_xor(s, off, 64);
    if (j == 0) out[b] = m2 + __logf(s) - numer;
}

// ---------------------------------------------------------------------------
extern "C" void kernel_launch(void* const* d_in, const int* in_sizes, int n_in,
                              void* d_out, int out_size, void* d_ws, size_t ws_size,
                              hipStream_t stream) {
    const int*   inputs      = (const int*)  d_in[0];
    const int*   tags        = (const int*)  d_in[1];
    const float* emb_table   = (const float*)d_in[2];
    const float* W1          = (const float*)d_in[3];
    const float* b1          = (const float*)d_in[4];
    const float* W2          = (const float*)d_in[5];
    const float* b2          = (const float*)d_in[6];
    const float* start_trans = (const float*)d_in[7];
    const float* end_trans   = (const float*)d_in[8];
    const float* transitions = (const float*)d_in[9];
    float* out = (float*)d_out;

    // ws: em bf16 (32 MiB) | W1f frags (28 KB) | W2f frags (16 KB)
    unsigned short* em = (unsigned short*)d_ws;
    uint4* W1f = (uint4*)((char*)d_ws + (size_t)BS_*T_*2);
    uint4* W2f = W1f + 7*4*64;

    prep_kernel<<<dim3(1), dim3(256), 0, stream>>>(W1, W2, W1f, W2f);
    mlp_kernel<<<dim3(BS_/64), dim3(256), 0, stream>>>(
        inputs, emb_table, b1, b2, W1f, W2f, em);
    crf_kernel<<<dim3(B_), dim3(64), 0, stream>>>(
        inputs, tags, em, start_trans, end_trans, transitions, out);
}

// Round 4
// 337.173 us; speedup vs baseline: 2.2934x; 1.1005x over previous
//
#include <hip/hip_runtime.h>

#define B_ 512
#define S_ 512
#define E_ 128
#define H_ 100
#define T_ 64
#define BS_ (B_*S_)

typedef __attribute__((ext_vector_type(8))) short bf16x8;
typedef __attribute__((ext_vector_type(4))) float f32x4;
typedef __attribute__((ext_vector_type(2))) float f32x2;
union U16x4 { uint4 u; bf16x8 s; };

__device__ __forceinline__ unsigned f2bf1(float x){
    unsigned u = __float_as_uint(x);
    return (u + 0x7FFFu + ((u>>16)&1u)) >> 16;
}
__device__ __forceinline__ float bf2f(unsigned short h){
    return __uint_as_float(((unsigned)h)<<16);
}
__device__ __forceinline__ float rfl_f(float x){
    return __uint_as_float(__builtin_amdgcn_readfirstlane(__float_as_uint(x)));
}

// ---------------------------------------------------------------------------
// Prep: W1/W2 bf16 MFMA B-fragment images (k-map: k=(lane>>4)*8+i).
// ---------------------------------------------------------------------------
__global__ void prep_kernel(const float* __restrict__ W1, const float* __restrict__ W2,
                            uint4* __restrict__ W1f, uint4* __restrict__ W2f)
{
    const int tid = threadIdx.x;
    for (int idx = tid; idx < 7*4*64; idx += 256) {
        int lane = idx & 63, kt = (idx>>6)&3, nt = idx>>8;
        int n = nt*16 + (lane&15);
        int kb = kt*32 + (lane>>4)*8;
        unsigned wv[4];
        #pragma unroll
        for (int p = 0; p < 4; ++p) {
            float v0 = (n < H_) ? W1[(kb+2*p  )*H_ + n] : 0.f;
            float v1 = (n < H_) ? W1[(kb+2*p+1)*H_ + n] : 0.f;
            wv[p] = f2bf1(v0) | (f2bf1(v1) << 16);
        }
        W1f[idx] = make_uint4(wv[0],wv[1],wv[2],wv[3]);
    }
    for (int idx = tid; idx < 4*4*64; idx += 256) {
        int lane = idx & 63, kt = (idx>>6)&3, nt = idx>>8;
        int n = nt*16 + (lane&15);
        int kb = kt*32 + (lane>>4)*8;
        unsigned wv[4];
        #pragma unroll
        for (int p = 0; p < 4; ++p) {
            int k0 = kb+2*p, k1 = kb+2*p+1;
            float v0 = (k0 < H_) ? W2[k0*T_ + n] : 0.f;
            float v1 = (k1 < H_) ? W2[k1*T_ + n] : 0.f;
            wv[p] = f2bf1(v0) | (f2bf1(v1) << 16);
        }
        W2f[idx] = make_uint4(wv[0],wv[1],wv[2],wv[3]);
    }
}

// ---------------------------------------------------------------------------
// MLP: A-fragments built directly in registers from the gather (k-slices are
// contiguous per lane) -> no X-LDS stage, no __syncthreads. LDS only for the
// wave-local GEMM1->GEMM2 transpose (16 KB).
// ---------------------------------------------------------------------------
__global__ __launch_bounds__(256, 4) void mlp_kernel(
    const int* __restrict__ inputs, const float* __restrict__ tbl,
    const float* __restrict__ b1, const float* __restrict__ b2,
    const uint4* __restrict__ W1f, const uint4* __restrict__ W2f,
    unsigned short* __restrict__ em)
{
    __shared__ uint4 sA2[1024];    // 16 KB; per-wave A2 frag staging

    const int tid  = threadIdx.x;
    const int lane = tid & 63;
    const int w    = tid >> 6;
    const int col  = lane & 15;
    const int hi   = lane >> 4;
    const int rowin = hi * 4;      // C/D: col=lane&15, row=(lane>>4)*4+reg (m89)

    const int rg = blockIdx.x*64 + w*16 + col;
    const int i0 = inputs[rg*3+0], i1 = inputs[rg*3+1], i2 = inputs[rg*3+2];
    const float4* r0 = (const float4*)tbl + (size_t)i0*(E_/4);
    const float4* r1 = (const float4*)tbl + (size_t)i1*(E_/4);
    const float4* r2 = (const float4*)tbl + (size_t)i2*(E_/4);

    // A fragments straight from global: lane needs k = kt*32 + hi*8 + 0..7
    U16x4 a[4];
    #pragma unroll
    for (int kt = 0; kt < 4; ++kt) {
        int fo = kt*8 + hi*2;
        float4 x0 = r0[fo], y0 = r0[fo+1];
        float4 x1 = r1[fo], y1 = r1[fo+1];
        float4 x2 = r2[fo], y2 = r2[fo+1];
        float v0 = x0.x+x1.x+x2.x, v1 = x0.y+x1.y+x2.y;
        float v2 = x0.z+x1.z+x2.z, v3 = x0.w+x1.w+x2.w;
        float v4 = y0.x+y1.x+y2.x, v5 = y0.y+y1.y+y2.y;
        float v6 = y0.z+y1.z+y2.z, v7 = y0.w+y1.w+y2.w;
        a[kt].u = make_uint4(f2bf1(v0)|(f2bf1(v1)<<16), f2bf1(v2)|(f2bf1(v3)<<16),
                             f2bf1(v4)|(f2bf1(v5)<<16), f2bf1(v6)|(f2bf1(v7)<<16));
    }

    // GEMM1: h(16x112) = X(16x128) @ W1(128x112); W1 frags from global (L2)
    f32x4 acc1[7];
    #pragma unroll
    for (int nt = 0; nt < 7; ++nt) {
        int n = nt*16 + col;
        float bv = (n < H_) ? b1[n] : 0.f;
        f32x4 c; c[0]=bv; c[1]=bv; c[2]=bv; c[3]=bv;
        #pragma unroll
        for (int k = 0; k < 4; ++k) {
            U16x4 bfr; bfr.u = W1f[(nt*4+k)*64 + lane];
            c = __builtin_amdgcn_mfma_f32_16x16x32_bf16(a[k].s, bfr.s, c, 0,0,0);
        }
        acc1[nt] = c;
    }
    #pragma unroll
    for (int nt = 0; nt < 7; ++nt)
        #pragma unroll
        for (int rr = 0; rr < 4; ++rr) {
            float x = acc1[nt][rr];
            acc1[nt][rr] = 1.f - 2.f/(__expf(2.f*x)+1.f);
        }

    // A2 staging (wave-local transpose): pad k2=112..127 with zeros
    if (lane >= 32) sA2[(w*4+3)*64 + lane] = make_uint4(0,0,0,0);
    unsigned short* A2h = (unsigned short*)sA2;
    #pragma unroll
    for (int nt = 0; nt < 7; ++nt)
        #pragma unroll
        for (int rr = 0; rr < 4; ++rr) {
            int k2 = nt*16 + col;
            int kt2 = k2 >> 5, g2 = (k2>>3)&3, i2v = k2&7;
            int u4idx = (w*4 + kt2)*64 + g2*16 + (rowin + rr);
            A2h[u4idx*8 + i2v] = (unsigned short)f2bf1(acc1[nt][rr]);
        }
    __builtin_amdgcn_wave_barrier();

    // GEMM2: em(16x64) = h(16x128pad) @ W2; store bf16
    U16x4 a2[4];
    #pragma unroll
    for (int k = 0; k < 4; ++k) a2[k].u = sA2[(w*4+k)*64 + lane];
    #pragma unroll
    for (int nt2 = 0; nt2 < 4; ++nt2) {
        float bv = b2[nt2*16 + col];
        f32x4 c; c[0]=bv; c[1]=bv; c[2]=bv; c[3]=bv;
        #pragma unroll
        for (int k = 0; k < 4; ++k) {
            U16x4 bfr; bfr.u = W2f[(nt2*4+k)*64 + lane];
            c = __builtin_amdgcn_mfma_f32_16x16x32_bf16(a2[k].s, bfr.s, c, 0,0,0);
        }
        #pragma unroll
        for (int rr = 0; rr < 4; ++rr) {
            size_t row = (size_t)(blockIdx.x*64 + w*16 + rowin + rr);
            em[row*T_ + nt2*16 + col] = (unsigned short)f2bf1(c[rr]);
        }
    }
}

// ---------------------------------------------------------------------------
// CRF scan in LINEAR space: a_{t+1,j} = (sum_i a_i E_ij) * exp(em_tj), with
// per-step rescale by readfirstlane(a) (exact math; only range matters).
// Critical chain: write a -> 16x ds_read_b128 -> FMA tree -> 2 muls -> select.
// exp(em) and log(scale) are off-chain. No exp/log on the chain at all.
// ---------------------------------------------------------------------------
__global__ __launch_bounds__(64) void crf_kernel(
    const int* __restrict__ inputs, const int* __restrict__ tags,
    const unsigned short* __restrict__ em, const float* __restrict__ start_trans,
    const float* __restrict__ end_trans, const float* __restrict__ trans,
    float* __restrict__ out)
{
    __shared__ unsigned short sem[2][8*T_];   // 2 x 1 KB em staging
    __shared__ float pbuf[T_];

    const int b = blockIdx.x;
    const int j = threadIdx.x;
    const unsigned short* em_b = em + (size_t)b*S_*T_;
    const int* tags_b = tags + b*S_;
    const int* in_b = inputs + (size_t)b*S_*3;

    // mask ballots + numerator
    unsigned long long mball[8];
    float partial = 0.f;
    #pragma unroll
    for (int g = 0; g < 8; ++g) {
        int t = g*64 + j;
        int a0 = in_b[t*3+0], a1 = in_b[t*3+1], a2 = in_b[t*3+2];
        bool mk = ((a0 | a1 | a2) != 0);
        mball[g] = __ballot(mk);
        if (t >= 1 && mk) {
            int tp = tags_b[t-1], tc = tags_b[t];
            partial += trans[tp*T_ + tc] + bf2f(em_b[(size_t)t*T_ + tc]);
        }
    }
    int mcount = 0;
    #pragma unroll
    for (int g = 0; g < 8; ++g) mcount += __popcll(mball[g]);
    mball[0] &= ~1ull;
    #pragma unroll
    for (int off = 32; off >= 1; off >>= 1) partial += __shfl_xor(partial, off, 64);
    const int tag0 = tags_b[0];
    int se = mcount - 1; if (se < 0) se = 0;
    const int last_tag = tags_b[se];
    const float numer = partial + start_trans[tag0] + bf2f(em_b[tag0]) + end_trans[last_tag];

    // E column j as f32x2 pairs (constant over scan)
    f32x2 E2[32];
    #pragma unroll
    for (int i = 0; i < 32; ++i) {
        f32x2 e; e.x = __expf(trans[(2*i)*T_ + j]); e.y = __expf(trans[(2*i+1)*T_ + j]);
        E2[i] = e;
    }

    // init: a = exp(alpha0 - m), ls = m
    float x0v = start_trans[j] + bf2f(em_b[j]);
    float ls = rfl_f(x0v);
    float a = __expf(x0v - ls);

    // group staging: sem[g&1] holds group g; eg[] = exp(em) for current group
    const uint4* em4 = (const uint4*)em_b;
    uint4 gbuf = em4[j];
    ((uint4*)sem[0])[j] = gbuf;
    __builtin_amdgcn_wave_barrier();
    float eg[8];
    #pragma unroll
    for (int c = 0; c < 8; ++c) eg[c] = __expf(bf2f(sem[0][c*T_ + j]));
    gbuf = em4[64 + j];

    for (int g = 0; g < 64; ++g) {
        // stage next group + issue its u16 reads (results consumed after steps)
        unsigned short raw16[8];
        if (g < 63) {
            ((uint4*)sem[(g+1)&1])[j] = gbuf;
            __builtin_amdgcn_wave_barrier();
            #pragma unroll
            for (int c = 0; c < 8; ++c) raw16[c] = sem[(g+1)&1][c*T_ + j];
            if (g < 62) gbuf = em4[(g+2)*64 + j];
        }
        const unsigned mg = (unsigned)((mball[g>>3] >> ((g&7)*8)) & 0xFFull);

        #pragma unroll
        for (int c = 0; c < 8; ++c) {
            pbuf[j] = a;                           // broadcast UNSCALED a
            __builtin_amdgcn_wave_barrier();
            float s    = rfl_f(a);                 // overlaps LDS round-trip
            float sinv = __builtin_amdgcn_rcpf(s);
            float logs = __logf(s);                // off-chain (ls accumulator)
            float keep = a * sinv;
            float dmul = eg[c] * sinv;
            const float4* pb4 = (const float4*)pbuf;
            f32x2 ac0={0.f,0.f}, ac1={0.f,0.f}, ac2={0.f,0.f}, ac3={0.f,0.f};
            #pragma unroll
            for (int q = 0; q < 4; ++q) {
                float4 A0 = pb4[4*q+0], A1 = pb4[4*q+1], A2v = pb4[4*q+2], A3 = pb4[4*q+3];
                f32x2 p0; p0.x=A0.x; p0.y=A0.y;  f32x2 p1; p1.x=A0.z; p1.y=A0.w;
                f32x2 p2; p2.x=A1.x; p2.y=A1.y;  f32x2 p3; p3.x=A1.z; p3.y=A1.w;
                f32x2 p4; p4.x=A2v.x;p4.y=A2v.y; f32x2 p5; p5.x=A2v.z;p5.y=A2v.w;
                f32x2 p6; p6.x=A3.x; p6.y=A3.y;  f32x2 p7; p7.x=A3.z; p7.y=A3.w;
                ac0 = p0*E2[8*q+0] + ac0;  ac1 = p1*E2[8*q+1] + ac1;
                ac2 = p2*E2[8*q+2] + ac2;  ac3 = p3*E2[8*q+3] + ac3;
                ac0 = p4*E2[8*q+4] + ac0;  ac1 = p5*E2[8*q+5] + ac1;
                ac2 = p6*E2[8*q+6] + ac2;  ac3 = p7*E2[8*q+7] + ac3;
            }
            f32x2 st = (ac0+ac1)+(ac2+ac3);
            float dot = st.x + st.y;
            float cand = dot * dmul;
            a = ((mg >> c) & 1u) ? cand : keep;
            ls += logs;
            __builtin_amdgcn_wave_barrier();
        }
        if (g < 63) {
            #pragma unroll
            for (int c = 0; c < 8; ++c) eg[c] = __expf(bf2f(raw16[c]));
        }
    }

    // denominator = ls + log(sum_j a_j * exp(end_j))
    float x = a * __expf(end_trans[j]);
    #pragma unroll
    for (int off = 32; off >= 1; off >>= 1) x += __shfl_xor(x, off, 64);
    if (j == 0) out[b] = ls + __logf(x) - numer;
}

// ---------------------------------------------------------------------------
extern "C" void kernel_launch(void* const* d_in, const int* in_sizes, int n_in,
                              void* d_out, int out_size, void* d_ws, size_t ws_size,
                              hipStream_t stream) {
    const int*   inputs      = (const int*)  d_in[0];
    const int*   tags        = (const int*)  d_in[1];
    const float* emb_table   = (const float*)d_in[2];
    const float* W1          = (const float*)d_in[3];
    const float* b1          = (const float*)d_in[4];
    const float* W2          = (const float*)d_in[5];
    const float* b2          = (const float*)d_in[6];
    const float* start_trans = (const float*)d_in[7];
    const float* end_trans   = (const float*)d_in[8];
    const float* transitions = (const float*)d_in[9];
    float* out = (float*)d_out;

    unsigned short* em = (unsigned short*)d_ws;            // 32 MiB bf16
    uint4* W1f = (uint4*)((char*)d_ws + (size_t)BS_*T_*2);
    uint4* W2f = W1f + 7*4*64;

    prep_kernel<<<dim3(1), dim3(256), 0, stream>>>(W1, W2, W1f, W2f);
    mlp_kernel<<<dim3(BS_/64), dim3(256), 0, stream>>>(
        inputs, emb_table, b1, b2, W1f, W2f, em);
    crf_kernel<<<dim3(B_), dim3(64), 0, stream>>>(
        inputs, tags, em, start_trans, end_trans, transitions, out);
}